// Round 11
// baseline (216.474 us; speedup 1.0000x reference)
//
#include <hip/hip_runtime.h>

// Problem constants (B=16, C1=C2=128, H=W=80, K=3, pad=1, stride=1)
#define HH 80
#define WW 80
#define C1 128
#define C2 128
#define NB 16
#define HWSZ 6400      // 80*80
#define KKT 1152       // C1*9 (GEMM K, reordered as k' = p*128 + c)

typedef __attribute__((ext_vector_type(8))) short bf16x8;
typedef __attribute__((ext_vector_type(4))) float f32x4;

union PkU   { uint4 v; uint d[4]; bf16x8 h; };
union CornU { uint4 v; uint d[4]; };
union HalfU { _Float16 h[2]; uint u; };

__device__ inline ushort f2bf(float f) {
  unsigned u = __float_as_uint(f);
  return (ushort)((u + 0x7FFFu + ((u >> 16) & 1u)) >> 16);
}

// packed f32x2 -> bf16x2 (RNE, identical rounding to f2bf)
__device__ inline uint cvtpk(float lo, float hi) {
  uint r;
  asm("v_cvt_pk_bf16_f32 %0, %1, %2" : "=v"(r) : "v"(lo), "v"(hi));
  return r;
}
__device__ inline float bfu_lo(uint w) { return __uint_as_float(w << 16); }
__device__ inline float bfu_hi(uint w) { return __uint_as_float(w & 0xFFFF0000u); }

// async global->LDS, 16B per lane, LDS dest = wave-uniform base (+lane*16 by HW)
// NOTE: completion tracked by vmcnt; CALLER must s_waitcnt before ds_read.
// Global SOURCE address is per-lane (m173): swizzles go on the source side.
__device__ inline void gload_lds16(const ushort* g, ushort* l) {
  __builtin_amdgcn_global_load_lds(
      (const __attribute__((address_space(1))) void*)g,
      (__attribute__((address_space(3))) void*)l, 16, 0, 0);
}

// ---------------------------------------------------------------------------
// Kernel A+B merged: transpose x -> xt (blocks 0..3199), weight prep
// (blocks 3200..3919), and 256B zero page for OOB gathers (block 3200).
// ---------------------------------------------------------------------------
__global__ __launch_bounds__(256) void xpose_prep_kernel(
    const float* __restrict__ x, ushort* __restrict__ xt,
    const float* __restrict__ w, const float* __restrict__ ow,
    ushort* __restrict__ wbf, ushort* __restrict__ wobf,
    ushort* __restrict__ zpad) {
  __shared__ float ts[64][65];
  const int idx = blockIdx.x;
  const int tid = threadIdx.x;

  if (idx < 3200) {
    const int b = idx / 200;
    const int rem = idx % 200;
    const int c0 = (rem / 100) * 64;
    const int hw0 = (rem % 100) * 64;
    const int lane = tid & 63;

    #pragma unroll
    for (int it = 0; it < 16; it++) {
      int cl = (tid >> 6) + it * 4;
      ts[cl][lane] = x[((size_t)(b * C1 + c0 + cl)) * HWSZ + hw0 + lane];
    }
    __syncthreads();

    #pragma unroll
    for (int it = 0; it < 2; it++) {
      int u = tid + it * 256;
      int j = u >> 3, cg = u & 7;
      CornU pk;
      #pragma unroll
      for (int m = 0; m < 4; m++)
        pk.d[m] = cvtpk(ts[cg * 8 + 2 * m][j], ts[cg * 8 + 2 * m + 1][j]);
      *(uint4*)(xt + ((size_t)b * HWSZ + hw0 + j) * C1 + c0 + cg * 8) = pk.v;
    }
  } else {
    if (idx == 3200 && tid < 16) {
      uint4 z = {0u, 0u, 0u, 0u};
      ((uint4*)zpad)[tid] = z;                   // 256B zero page
    }
    int o = (idx - 3200) * 256 + tid;            // 0..184319
    if (o < C2 * KKT) {
      int j  = o & 7;
      int ch = (o >> 3) & 127;
      int kt = o >> 12;
      int kg = (o >> 10) & 3;
      int kprime = kt * 32 + kg * 8 + j;
      int p = kprime >> 7;
      int c = kprime & 127;
      wbf[o] = f2bf(w[(size_t)ch * KKT + c * 9 + p]);
    } else {
      int o2 = o - C2 * KKT;
      int j  = o2 & 7;
      int ch = (o2 >> 3) & 31;
      int kt = o2 >> 10;
      int kg = (o2 >> 8) & 3;
      int kprime = kt * 32 + kg * 8 + j;
      int p = kprime >> 7;
      int c = kprime & 127;
      wobf[o2] = (ch < 18) ? f2bf(ow[(size_t)ch * KKT + c * 9 + p]) : (ushort)0;
    }
  }
}

// ---------------------------------------------------------------------------
// Kernel C (FUSED, LDS-dieted for 3 blocks/CU):
//   LDS = crd 4608 (8B packed entries) + w_pbuf 32768 + smp 16384 = 53760
//   (obuf overlaid into w_pbuf[1]; safe: phase-0 uses only w_pbuf[0]+smp,
//    obuf is wave-column-private, and main-loop stage_p(0) is ordered after
//    all phase-A reads by barrier1's lgkmcnt(0)+s_barrier.)
// crd entry: x = (y0:i16)<<16 | (x0:i16), y = (wy1:f16, wx1:f16) packed.
// Everything else is the r10 fused structure, frozen.
// ---------------------------------------------------------------------------
struct Geo { float f00, f01, f10, f11; int o00, o01, o10, o11; };

__device__ inline Geo make_geo(uint2 cd) {
  Geo g;
  int y0 = (int)(short)(cd.x >> 16);
  int x0 = (int)(short)(cd.x & 0xFFFFu);
  HalfU hu; hu.u = cd.y;
  float wy1 = (float)hu.h[0];
  float wx1 = (float)hu.h[1];
  float fy0 = ((unsigned)y0 < (unsigned)HH) ? (1.f - wy1) : 0.f;
  float fy1 = ((unsigned)(y0 + 1) < (unsigned)HH) ? wy1 : 0.f;
  float fx0 = ((unsigned)x0 < (unsigned)WW) ? (1.f - wx1) : 0.f;
  float fx1 = ((unsigned)(x0 + 1) < (unsigned)WW) ? wx1 : 0.f;
  g.f00 = fy0 * fx0; g.f01 = fy0 * fx1;
  g.f10 = fy1 * fx0; g.f11 = fy1 * fx1;
  int r0 = min(max(y0, 0), HH - 1), r1 = min(max(y0 + 1, 0), HH - 1);
  int q0 = min(max(x0, 0), WW - 1), q1 = min(max(x0 + 1, 0), WW - 1);
  g.o00 = (r0 * WW + q0) * C1; g.o01 = (r0 * WW + q1) * C1;
  g.o10 = (r1 * WW + q0) * C1; g.o11 = (r1 * WW + q1) * C1;
  return g;
}

__global__ __launch_bounds__(256) void dconv_fused_kernel(
    const ushort* __restrict__ xt, const ushort* __restrict__ wobf,
    const ushort* __restrict__ zpad, const float* __restrict__ ob,
    const ushort* __restrict__ wbf, const float* __restrict__ bias,
    float* __restrict__ out) {
  const int bid = blockIdx.x;                    // 0..1599; bid%8 = b%8 (XCD/batch)
  const int b = bid & 15;
  const int tile = bid >> 4;                     // 0..99
  const int h0 = (tile / 5) * 4;
  const int w0 = (tile % 5) * 16;
  const int tid = threadIdx.x;
  const int lane = tid & 63;
  const int wave = tid >> 6;
  const int q = lane >> 4, c15 = lane & 15;
  const int spos = wave * 16 + c15;

  __shared__ uint2  crd[9][64];                  // 4608 B (same-wave use only)
  __shared__ ushort w_pbuf[4][4096];             // 32 KB: weights of current p
  __shared__ ushort smp[4][16][128];             // 16 KB: [wave][pos][ch], swizzled

  ushort (*w_obuf)[1024] = reinterpret_cast<ushort (*)[1024]>(&w_pbuf[0][0]);
  float  (*obuf)[64]     = reinterpret_cast<float (*)[64]>(&w_pbuf[1][0]);  // overlay

  const ushort* xtb = xt + (size_t)b * HWSZ * C1;

  // ===================== Phase 0: offset conv (r9 body) =====================
  {
    f32x4 acc0 = {0.f, 0.f, 0.f, 0.f}, acc1 = {0.f, 0.f, 0.f, 0.f};

    #pragma unroll 1
    for (int p = 0; p < 9; ++p) {
      asm volatile("s_waitcnt lgkmcnt(0)" ::: "memory");
      __builtin_amdgcn_s_barrier();

      // stage wobf[4p+wave] (2 KB) into w_obuf[wave]  (2 vmem instrs)
      #pragma unroll
      for (int j = 0; j < 2; ++j)
        gload_lds16(wobf + (size_t)(4 * p + wave) * 1024 + (j * 64 + lane) * 8,
                    &w_obuf[wave][j * 512]);

      // gather this wave's 16 regular-grid records into smp[wave] (4 instrs)
      {
        const int row = h0 + wave + p / 3 - 1;
        #pragma unroll
        for (int jj = 0; jj < 4; ++jj) {
          const int pos = 4 * jj + q;            // q doubles as jp
          const int col = w0 + pos + p % 3 - 1;
          const int sl = c15 ^ (pos & 7);        // source-side bank swizzle
          const ushort* src =
              ((unsigned)row < (unsigned)HH && (unsigned)col < (unsigned)WW)
                  ? xtb + ((size_t)row * WW + col) * C1 + sl * 8
                  : zpad + sl * 8;
          gload_lds16(src, &smp[wave][4 * jj][0]);
        }
      }

      asm volatile("s_waitcnt vmcnt(0)" ::: "memory");
      __builtin_amdgcn_s_barrier();              // stages + gathers landed

      // mini-GEMM: 4 chunks x {a0,a1}; B-frag slice (4kk+q) of pos c15
      #pragma unroll
      for (int kk = 0; kk < 4; ++kk) {
        bf16x8 bfrag = *(const bf16x8*)
            &smp[wave][c15][(((4 * kk + q) ^ (c15 & 7)) * 8)];
        bf16x8 a0 = *(const bf16x8*)&w_obuf[kk][(q * 32 + c15) * 8];
        bf16x8 a1 = *(const bf16x8*)&w_obuf[kk][(q * 32 + 16 + c15) * 8];
        acc0 = __builtin_amdgcn_mfma_f32_16x16x32_bf16(a0, bfrag, acc0, 0, 0, 0);
        acc1 = __builtin_amdgcn_mfma_f32_16x16x32_bf16(a1, bfrag, acc1, 0, 0, 0);
      }
    }

    // epilogue -> LDS obuf (D col = c15 = pos, row = q*4+r = ch)
    // obuf lives in w_pbuf[1]: phase 0 never touches it, and main-loop
    // stage_p is ordered after phase-A reads by barrier1.
    #pragma unroll
    for (int r = 0; r < 4; r++) {
      int ch = q * 4 + r;                        // 0..15 all valid
      obuf[ch][spos] = acc0[r] + ob[ch];
    }
    if (q == 0) {
      obuf[16][spos] = acc1[0] + ob[16];
      obuf[17][spos] = acc1[1] + ob[17];
    }
  }

  // ===== Phase A: coords from obuf (same-wave column -> no barrier) =====
  {
    const int ho = h0 + wave, wo = w0 + c15;
    #pragma unroll
    for (int p = 0; p < 9; ++p) {
      if ((p & 3) == q) {
        float dy = obuf[2 * p][spos];
        float dx = obuf[2 * p + 1][spos];
        float py = (float)(ho - 1 + p / 3) + dy;
        float px = (float)(wo - 1 + p % 3) + dx;
        float y0f = floorf(py), x0f = floorf(px);
        int y0 = (int)y0f, x0 = (int)x0f;
        HalfU hu;
        hu.h[0] = (_Float16)(py - y0f);
        hu.h[1] = (_Float16)(px - x0f);
        uint xy = ((uint)(ushort)(short)y0 << 16) | (uint)(ushort)(short)x0;
        crd[p][spos] = make_uint2(xy, hu.u);
      }
    }
  }

  // ===================== Main loop: r8/r9 frozen structure ==================
  const int jp = lane >> 4;
  const int s  = lane & 15;

  float4 fw[4];          // bilinear corner weights for this wave-lane's 4 pos
  uint4  cr[4][4];       // gathered corners: [jj][corner], 16B each

  auto issue_p = [&](int p) {
    #pragma unroll
    for (int jj = 0; jj < 4; ++jj) {
      Geo gg = make_geo(crd[p][wave * 16 + 4 * jj + jp]);
      fw[jj] = make_float4(gg.f00, gg.f01, gg.f10, gg.f11);
      const ushort* cp = xtb + s * 8;
      cr[jj][0] = *(const uint4*)(cp + gg.o00);
      cr[jj][1] = *(const uint4*)(cp + gg.o01);
      cr[jj][2] = *(const uint4*)(cp + gg.o10);
      cr[jj][3] = *(const uint4*)(cp + gg.o11);
    }
  };

  auto stage_p = [&](int p) {
    #pragma unroll
    for (int j = 0; j < 8; ++j)
      gload_lds16(wbf + ((size_t)(4 * p + wave)) * 4096 + (j * 64 + lane) * 8,
                  w_pbuf[wave] + j * 512);
  };

  auto bilinear_write = [&]() {
    #pragma unroll
    for (int jj = 0; jj < 4; ++jj) {
      const int pos = 4 * jj + jp;
      CornU u0, u1, u2, u3;
      PkU pk;
      u0.v = cr[jj][0]; u1.v = cr[jj][1]; u2.v = cr[jj][2]; u3.v = cr[jj][3];
      const float f00 = fw[jj].x, f01 = fw[jj].y, f10 = fw[jj].z, f11 = fw[jj].w;
      #pragma unroll
      for (int d = 0; d < 4; ++d) {
        float ol = f00 * bfu_lo(u0.d[d]);
        float oh = f00 * bfu_hi(u0.d[d]);
        ol = fmaf(f01, bfu_lo(u1.d[d]), ol);
        oh = fmaf(f01, bfu_hi(u1.d[d]), oh);
        ol = fmaf(f10, bfu_lo(u2.d[d]), ol);
        oh = fmaf(f10, bfu_hi(u2.d[d]), oh);
        ol = fmaf(f11, bfu_lo(u3.d[d]), ol);
        oh = fmaf(f11, bfu_hi(u3.d[d]), oh);
        pk.d[d] = cvtpk(ol, oh);
      }
      char* wp = (char*)&smp[wave][pos][0] + ((s * 16) ^ ((pos & 7) << 4));
      *(uint4*)wp = pk.v;
    }
  };

  f32x4 acc[8];
  #pragma unroll
  for (int mt = 0; mt < 8; mt++) acc[mt] = (f32x4){0.f, 0.f, 0.f, 0.f};

  // prologue: gathers for p=0 (crd ready: same-wave DS ordering)
  issue_p(0);
  asm volatile("" ::: "memory");                 // pin g(0) oldest

  #pragma unroll 1
  for (int p = 0; p < 9; ++p) {
    // barrier1: everyone done reading w_pbuf/smp/obuf of previous phase
    // (ds_reads consumed => lgkm clean; raw barrier, NO vmcnt drain)
    asm volatile("s_waitcnt lgkmcnt(0)" ::: "memory");
    __builtin_amdgcn_s_barrier();

    stage_p(p);                                  // vmem order: stage(p)...
    asm volatile("" ::: "memory");

    bilinear_write();                            // consumes g(p) (auto-wait)

    if (p < 8) {
      issue_p(p + 1);                            // ...then g(p+1) youngest
      asm volatile("" ::: "memory");
      asm volatile("s_waitcnt vmcnt(16)" ::: "memory");  // retire stage(p) only
    } else {
      asm volatile("s_waitcnt vmcnt(0)" ::: "memory");
    }
    __builtin_amdgcn_sched_barrier(0);
    asm volatile("s_waitcnt lgkmcnt(0)" ::: "memory");   // smp writes done
    __builtin_amdgcn_s_barrier();                // barrier2: all stages landed

    // chunk-loop: 4 chunks of p, B-frag from swizzled smp, A-frags from w_pbuf
    #pragma unroll
    for (int kk = 0; kk < 4; ++kk) {
      const char* bp = (const char*)&smp[wave][c15][0] +
                       ((kk * 64 + q * 16) ^ ((c15 & 7) << 4));
      bf16x8 bfrag = *(const bf16x8*)bp;
      #pragma unroll
      for (int mt = 0; mt < 8; mt++) {
        bf16x8 afrag = *(const bf16x8*)&w_pbuf[kk][(q * 128 + mt * 16 + c15) * 8];
        acc[mt] = __builtin_amdgcn_mfma_f32_16x16x32_bf16(afrag, bfrag, acc[mt], 0, 0, 0);
      }
    }
  }

  // ---- epilogue
  {
    const int ho = h0 + wave, wo = w0 + c15;
    #pragma unroll
    for (int mt = 0; mt < 8; mt++) {
      #pragma unroll
      for (int r = 0; r < 4; r++) {
        int ch = mt * 16 + q * 4 + r;
        out[((size_t)b * C2 + ch) * HWSZ + ho * WW + wo] = acc[mt][r] + bias[ch];
      }
    }
  }
}

// ---------------------------------------------------------------------------
extern "C" void kernel_launch(void* const* d_in, const int* in_sizes, int n_in,
                              void* d_out, int out_size, void* d_ws, size_t ws_size,
                              hipStream_t stream) {
  const float* x    = (const float*)d_in[0];   // (16,128,80,80)
  const float* ow   = (const float*)d_in[1];   // (18,128,3,3)
  const float* ob   = (const float*)d_in[2];   // (18,)
  const float* wgt  = (const float*)d_in[3];   // (128,128,3,3)
  const float* bias = (const float*)d_in[4];   // (128,)
  float* out = (float*)d_out;                  // (16,128,80,80)

  // workspace layout (xt first for 16B alignment)
  ushort* xt   = (ushort*)d_ws;                          // 26.2 MB
  ushort* wbf  = (ushort*)((char*)d_ws + 26214400);      // 288 KB
  ushort* wobf = (ushort*)((char*)d_ws + 26214400 + 294912);           // 72 KB
  ushort* zpad = (ushort*)((char*)d_ws + 26214400 + 294912 + 73728);   // 256 B

  xpose_prep_kernel<<<dim3(3920), dim3(256), 0, stream>>>(x, xt, wgt, ow, wbf, wobf, zpad);
  dconv_fused_kernel<<<dim3(1600), dim3(256), 0, stream>>>(xt, wobf, zpad, ob, wbf, bias, out);
}